// Round 3
// baseline (720.472 us; speedup 1.0000x reference)
//
#include <hip/hip_runtime.h>

typedef short bf16x8 __attribute__((ext_vector_type(8)));
typedef float f32x4 __attribute__((ext_vector_type(4)));

#define MFMA16(a, b, c) __builtin_amdgcn_mfma_f32_16x16x32_bf16((a), (b), (c), 0, 0, 0)

static constexpr int T_LEN = 512;
static constexpr int F_DIM = 64;
static constexpr int NB    = 8;    // batch rows per block (8 -> 512 blocks -> 2 blocks/CU)

__device__ __forceinline__ float fast_tanh(float z) {
  float e = __expf(2.0f * z);
  return 1.0f - 2.0f / (e + 1.0f);
}

// split fp32 v into hi/lo bf16 bit patterns (truncation; lo captures next 8 bits)
__device__ __forceinline__ void split1(float v, unsigned short &h, unsigned short &l) {
  unsigned u  = __float_as_uint(v);
  unsigned uh = u & 0xffff0000u;
  h = (unsigned short)(u >> 16);
  float rem = v - __uint_as_float(uh);
  l = (unsigned short)(__float_as_uint(rem) >> 16);
}

__device__ __forceinline__ void split8(const float4 &a, const float4 &b,
                                       bf16x8 &h8, bf16x8 &l8) {
  float v[8] = {a.x, a.y, a.z, a.w, b.x, b.y, b.z, b.w};
#pragma unroll
  for (int i = 0; i < 8; ++i) {
    unsigned short h, l;
    split1(v[i], h, l);
    h8[i] = (short)h;
    l8[i] = (short)l;
  }
}

// One full RNN step (m-cell then p-cell) for this block's 8 batch rows.
// cur buffers (_c) receive new state; prev buffers (_p) hold old state.
// A-frag rows duplicate (arow = l15&7); C rows >=8 are duplicates -> writes
// guarded by g<2 (brow = 4g+r < 8).
template<bool FIN>
__device__ __forceinline__ void step_cells(
    int arow, int g, int j,
    const bf16x8 &xh0, const bf16x8 &xl0, const bf16x8 &xh1, const bf16x8 &xl1,
    const bf16x8 (&BmH)[6], const bf16x8 (&BmL)[6],
    const bf16x8 (&BpH)[6], const bf16x8 (&BpL)[6],
    float bias_m, float bias_p,
    unsigned short (*smh_c)[72], unsigned short (*sml_c)[72],
    unsigned short (*smh_p)[72], unsigned short (*sml_p)[72],
    unsigned short (*sph_c)[72], unsigned short (*spl_c)[72],
    unsigned short (*sph_p)[72], unsigned short (*spl_p)[72],
    float (*mfin)[68], float (*pfin)[68])
{
  const int g8 = g * 8;
  // p_old fragments (reused by both cells; buffer not rewritten this step)
  bf16x8 ph0 = *(const bf16x8 *)&sph_p[arow][g8];
  bf16x8 pl0 = *(const bf16x8 *)&spl_p[arow][g8];
  bf16x8 ph1 = *(const bf16x8 *)&sph_p[arow][32 + g8];
  bf16x8 pl1 = *(const bf16x8 *)&spl_p[arow][32 + g8];

  // ---------------- metrics cell: in = [x | p_old | m_old]
  {
    bf16x8 mh0 = *(const bf16x8 *)&smh_p[arow][g8];
    bf16x8 ml0 = *(const bf16x8 *)&sml_p[arow][g8];
    bf16x8 mh1 = *(const bf16x8 *)&smh_p[arow][32 + g8];
    bf16x8 ml1 = *(const bf16x8 *)&sml_p[arow][32 + g8];
    f32x4 a0 = {bias_m, bias_m, bias_m, bias_m};
    f32x4 a1 = {0.f, 0.f, 0.f, 0.f};
    f32x4 a2 = {0.f, 0.f, 0.f, 0.f};
    f32x4 a3 = {0.f, 0.f, 0.f, 0.f};
    a0 = MFMA16(xh0, BmH[0], a0);
    a1 = MFMA16(xl0, BmH[0], a1);
    a2 = MFMA16(xh0, BmL[0], a2);
    a3 = MFMA16(xh1, BmH[1], a3);
    a0 = MFMA16(xl1, BmH[1], a0);
    a1 = MFMA16(xh1, BmL[1], a1);
    a2 = MFMA16(ph0, BmH[2], a2);
    a3 = MFMA16(pl0, BmH[2], a3);
    a0 = MFMA16(ph0, BmL[2], a0);
    a1 = MFMA16(ph1, BmH[3], a1);
    a2 = MFMA16(pl1, BmH[3], a2);
    a3 = MFMA16(ph1, BmL[3], a3);
    a0 = MFMA16(mh0, BmH[4], a0);
    a1 = MFMA16(ml0, BmH[4], a1);
    a2 = MFMA16(mh0, BmL[4], a2);
    a3 = MFMA16(mh1, BmH[5], a3);
    a0 = MFMA16(ml1, BmH[5], a0);
    a1 = MFMA16(mh1, BmL[5], a1);
    if (g < 2) {
#pragma unroll
      for (int r = 0; r < 4; ++r) {
        float z  = (a0[r] + a1[r]) + (a2[r] + a3[r]);
        float tv = fast_tanh(z);
        unsigned short h, l;
        split1(tv, h, l);
        const int brow = g * 4 + r;
        smh_c[brow][j] = h;
        sml_c[brow][j] = l;
        if (FIN) mfin[brow][j] = tv;
      }
    }
  }
  __syncthreads();   // m_new visible to all waves
  // ---------------- price cell: in = [x | m_new | p_old]
  {
    bf16x8 nh0 = *(const bf16x8 *)&smh_c[arow][g8];
    bf16x8 nl0 = *(const bf16x8 *)&sml_c[arow][g8];
    bf16x8 nh1 = *(const bf16x8 *)&smh_c[arow][32 + g8];
    bf16x8 nl1 = *(const bf16x8 *)&sml_c[arow][32 + g8];
    f32x4 a0 = {bias_p, bias_p, bias_p, bias_p};
    f32x4 a1 = {0.f, 0.f, 0.f, 0.f};
    f32x4 a2 = {0.f, 0.f, 0.f, 0.f};
    f32x4 a3 = {0.f, 0.f, 0.f, 0.f};
    a0 = MFMA16(xh0, BpH[0], a0);
    a1 = MFMA16(xl0, BpH[0], a1);
    a2 = MFMA16(xh0, BpL[0], a2);
    a3 = MFMA16(xh1, BpH[1], a3);
    a0 = MFMA16(xl1, BpH[1], a0);
    a1 = MFMA16(xh1, BpL[1], a1);
    a2 = MFMA16(nh0, BpH[2], a2);
    a3 = MFMA16(nl0, BpH[2], a3);
    a0 = MFMA16(nh0, BpL[2], a0);
    a1 = MFMA16(nh1, BpH[3], a1);
    a2 = MFMA16(nl1, BpH[3], a2);
    a3 = MFMA16(nh1, BpL[3], a3);
    a0 = MFMA16(ph0, BpH[4], a0);
    a1 = MFMA16(pl0, BpH[4], a1);
    a2 = MFMA16(ph0, BpL[4], a2);
    a3 = MFMA16(ph1, BpH[5], a3);
    a0 = MFMA16(pl1, BpH[5], a0);
    a1 = MFMA16(ph1, BpL[5], a1);
    if (g < 2) {
#pragma unroll
      for (int r = 0; r < 4; ++r) {
        float z  = (a0[r] + a1[r]) + (a2[r] + a3[r]);
        float tv = fast_tanh(z);
        unsigned short h, l;
        split1(tv, h, l);
        const int brow = g * 4 + r;
        sph_c[brow][j] = h;
        spl_c[brow][j] = l;
        if (FIN) pfin[brow][j] = tv;
      }
    }
  }
  __syncthreads();   // p_new visible; prev buffers free for overwrite next step
}

__global__ __launch_bounds__(256, 2)
void mr_rnn_kernel(const float *__restrict__ x,
                   const float *__restrict__ mWih, const float *__restrict__ mWhh,
                   const float *__restrict__ mbih, const float *__restrict__ mbhh,
                   const float *__restrict__ pWih, const float *__restrict__ pWhh,
                   const float *__restrict__ pbih, const float *__restrict__ pbhh,
                   const float *__restrict__ plW,  const float *__restrict__ plb,
                   const float *__restrict__ mlW,  const float *__restrict__ mlb,
                   float *__restrict__ out, int B)
{
  __shared__ __align__(16) unsigned short sm_hi[2][NB][72], sm_lo[2][NB][72];
  __shared__ __align__(16) unsigned short sp_hi[2][NB][72], sp_lo[2][NB][72];
  __shared__ __align__(16) float s_mfin[NB][68], s_pfin[NB][68];

  const int tid  = threadIdx.x;
  const int lane = tid & 63;
  const int q    = tid >> 6;       // wave id 0..3 -> output col tile
  const int l15  = lane & 15;      // B-col (j) within tile
  const int arow = l15 & (NB - 1); // A-row (batch) — rows duplicated, broadcast reads
  const int g    = lane >> 4;      // k-group
  const int j    = q * 16 + l15;   // output feature owned by this lane's wave
  const int b0   = blockIdx.x * NB;
  const int g8   = g * 8;

  // ---- build register-resident weight B-fragments: B[k][j] = W[j][k], hi/lo bf16
  bf16x8 BmH[6], BmL[6], BpH[6], BpL[6];
#pragma unroll
  for (int kt = 0; kt < 6; ++kt) {
    const int k0 = kt * 32 + g8;
#pragma unroll
    for (int i = 0; i < 8; ++i) {
      const int k = k0 + i;
      float wm = (k < 128) ? mWih[j * 128 + k] : mWhh[j * 64 + (k - 128)];
      float wp = (k < 128) ? pWih[j * 128 + k] : pWhh[j * 64 + (k - 128)];
      unsigned short h, l;
      split1(wm, h, l);
      BmH[kt][i] = (short)h; BmL[kt][i] = (short)l;
      split1(wp, h, l);
      BpH[kt][i] = (short)h; BpL[kt][i] = (short)l;
    }
  }
  const float bias_m = mbih[j] + mbhh[j];
  const float bias_p = pbih[j] + pbhh[j];

  // ---- zero the t=-1 state buffers (parity index 1)
  for (int idx = tid; idx < NB * 72; idx += 256) {
    const int bb = idx / 72, kk = idx % 72;
    sm_hi[1][bb][kk] = 0; sm_lo[1][bb][kk] = 0;
    sp_hi[1][bb][kk] = 0; sp_lo[1][bb][kk] = 0;
  }

  // ---- x stream: this lane covers batch b0+arow, features [g8,g8+8) and [32+g8,32+g8+8)
  const float *xrow = x + (size_t)(b0 + arow) * T_LEN * F_DIM;
  float4 A0, A1, A2, A3, C0, C1, C2, C3;
  A0 = *(const float4 *)(xrow + 0 * F_DIM + g8);
  A1 = *(const float4 *)(xrow + 0 * F_DIM + g8 + 4);
  A2 = *(const float4 *)(xrow + 0 * F_DIM + 32 + g8);
  A3 = *(const float4 *)(xrow + 0 * F_DIM + 32 + g8 + 4);
  C0 = *(const float4 *)(xrow + 1 * F_DIM + g8);
  C1 = *(const float4 *)(xrow + 1 * F_DIM + g8 + 4);
  C2 = *(const float4 *)(xrow + 1 * F_DIM + 32 + g8);
  C3 = *(const float4 *)(xrow + 1 * F_DIM + 32 + g8 + 4);
  bf16x8 xh0, xl0, xh1, xl1;
  split8(A0, A1, xh0, xl0);
  split8(A2, A3, xh1, xl1);
  __syncthreads();   // zero-init visible

#pragma unroll 1
  for (int t = 0; t < T_LEN - 2; t += 2) {
    // ---- step t (even): cur=0, prev=1; prefetch x(t+2) into A*
    A0 = *(const float4 *)(xrow + (size_t)(t + 2) * F_DIM + g8);
    A1 = *(const float4 *)(xrow + (size_t)(t + 2) * F_DIM + g8 + 4);
    A2 = *(const float4 *)(xrow + (size_t)(t + 2) * F_DIM + 32 + g8);
    A3 = *(const float4 *)(xrow + (size_t)(t + 2) * F_DIM + 32 + g8 + 4);
    step_cells<false>(arow, g, j, xh0, xl0, xh1, xl1, BmH, BmL, BpH, BpL,
                      bias_m, bias_p,
                      sm_hi[0], sm_lo[0], sm_hi[1], sm_lo[1],
                      sp_hi[0], sp_lo[0], sp_hi[1], sp_lo[1],
                      s_mfin, s_pfin);
    split8(C0, C1, xh0, xl0);
    split8(C2, C3, xh1, xl1);
    // ---- step t+1 (odd): cur=1, prev=0; prefetch x(t+3) into C*
    C0 = *(const float4 *)(xrow + (size_t)(t + 3) * F_DIM + g8);
    C1 = *(const float4 *)(xrow + (size_t)(t + 3) * F_DIM + g8 + 4);
    C2 = *(const float4 *)(xrow + (size_t)(t + 3) * F_DIM + 32 + g8);
    C3 = *(const float4 *)(xrow + (size_t)(t + 3) * F_DIM + 32 + g8 + 4);
    step_cells<false>(arow, g, j, xh0, xl0, xh1, xl1, BmH, BmL, BpH, BpL,
                      bias_m, bias_p,
                      sm_hi[1], sm_lo[1], sm_hi[0], sm_lo[0],
                      sp_hi[1], sp_lo[1], sp_hi[0], sp_lo[0],
                      s_mfin, s_pfin);
    split8(A0, A1, xh0, xl0);
    split8(A2, A3, xh1, xl1);
  }
  // ---- step 510: cur=0, prev=1
  step_cells<false>(arow, g, j, xh0, xl0, xh1, xl1, BmH, BmL, BpH, BpL,
                    bias_m, bias_p,
                    sm_hi[0], sm_lo[0], sm_hi[1], sm_lo[1],
                    sp_hi[0], sp_lo[0], sp_hi[1], sp_lo[1],
                    s_mfin, s_pfin);
  split8(C0, C1, xh0, xl0);
  split8(C2, C3, xh1, xl1);
  // ---- step 511: cur=1, prev=0 (writes fp32 finals)
  step_cells<true>(arow, g, j, xh0, xl0, xh1, xl1, BmH, BmL, BpH, BpL,
                   bias_m, bias_p,
                   sm_hi[1], sm_lo[1], sm_hi[0], sm_lo[0],
                   sp_hi[1], sp_lo[1], sp_hi[0], sp_lo[0],
                   s_mfin, s_pfin);

  // ---- heads (trailing __syncthreads inside step_cells orders s_*fin)
  if (tid < NB) {
    const int b = tid;
    float acc = plb[0];
#pragma unroll 1
    for (int k = 0; k < 64; ++k) acc += s_pfin[b][k] * plW[k];
    out[b0 + b] = acc;
  } else if (tid < NB + NB * 8) {
    const int r = tid - NB;
    const int b = r >> 3, e = r & 7;
    float acc = mlb[e];
#pragma unroll 1
    for (int k = 0; k < 64; ++k) acc += s_mfin[b][k] * mlW[e * 64 + k];
    out[(size_t)B + (size_t)(b0 + b) * 8 + e] = acc;
  }
}

extern "C" void kernel_launch(void* const* d_in, const int* in_sizes, int n_in,
                              void* d_out, int out_size, void* d_ws, size_t ws_size,
                              hipStream_t stream) {
  (void)n_in; (void)out_size; (void)d_ws; (void)ws_size;
  const float* x    = (const float*)d_in[0];
  const float* mWih = (const float*)d_in[1];
  const float* mWhh = (const float*)d_in[2];
  const float* mbih = (const float*)d_in[3];
  const float* mbhh = (const float*)d_in[4];
  const float* pWih = (const float*)d_in[5];
  const float* pWhh = (const float*)d_in[6];
  const float* pbih = (const float*)d_in[7];
  const float* pbhh = (const float*)d_in[8];
  const float* plW  = (const float*)d_in[9];
  const float* plb  = (const float*)d_in[10];
  const float* mlW  = (const float*)d_in[11];
  const float* mlb  = (const float*)d_in[12];
  const int B = in_sizes[0] / (T_LEN * F_DIM);
  const int nblk = B / NB;   // 512 blocks -> 2 blocks/CU -> 2 waves/SIMD
  mr_rnn_kernel<<<dim3(nblk), dim3(256), 0, stream>>>(
      x, mWih, mWhh, mbih, mbhh, pWih, pWhh, pbih, pbhh,
      plW, plb, mlW, mlb, (float*)d_out, B);
}

// Round 4
// 465.089 us; speedup vs baseline: 1.5491x; 1.5491x over previous
//
#include <hip/hip_runtime.h>

typedef short bf16x8 __attribute__((ext_vector_type(8)));
typedef float f32x4 __attribute__((ext_vector_type(4)));

#define MFMA16(a, b, c) __builtin_amdgcn_mfma_f32_16x16x32_bf16((a), (b), (c), 0, 0, 0)

static constexpr int T_LEN = 512;
static constexpr int F_DIM = 64;
static constexpr int NB    = 8;    // batch rows per block -> 512 blocks -> 2 blocks/CU

__device__ __forceinline__ float fast_tanh(float z) {
  float e = __expf(2.0f * z);
  return 1.0f - 2.0f / (e + 1.0f);
}

// fp32 -> bf16 round-to-nearest-even (bit pattern)
__device__ __forceinline__ unsigned short brne(float f) {
  unsigned u = __float_as_uint(f);
  return (unsigned short)((u + 0x7fffu + ((u >> 16) & 1u)) >> 16);
}

__device__ __forceinline__ void cvt8(const float4 &a, const float4 &b, bf16x8 &o) {
  o[0] = (short)brne(a.x); o[1] = (short)brne(a.y);
  o[2] = (short)brne(a.z); o[3] = (short)brne(a.w);
  o[4] = (short)brne(b.x); o[5] = (short)brne(b.y);
  o[6] = (short)brne(b.z); o[7] = (short)brne(b.w);
}

// One RNN step (m-cell then p-cell), all-bf16 operands, fp32 accum.
// PAR=0 (even t): valid C rows 0-7, writers g<2.  PAR=1 (odd t): valid C rows
// 8-15 (x frags of lanes l15>=8), writers g>=2.  A rows of the inactive half
// hold the OTHER step's x — harmless, their C rows are discarded.
template<int PAR, bool FIN>
__device__ __forceinline__ void step_cells(
    int arow, int g, int j,
    const bf16x8 &x0, const bf16x8 &x1,
    const bf16x8 (&Bm)[6], const bf16x8 (&Bp)[6],
    float bias_m, float bias_p,
    unsigned short (*sm_c)[72], unsigned short (*sm_p)[72],
    unsigned short (*sp_c)[72], unsigned short (*sp_p)[72],
    float (*mfin)[68], float (*pfin)[68])
{
  const int g8 = g * 8;
  const bool wr = (PAR == 0) ? (g < 2) : (g >= 2);
  const int gb  = (PAR == 0) ? g : (g - 2);
  // p_old fragments (used by both cells; buffer not rewritten this step)
  bf16x8 p0 = *(const bf16x8 *)&sp_p[arow][g8];
  bf16x8 p1 = *(const bf16x8 *)&sp_p[arow][32 + g8];

  // ---------------- metrics cell: in = [x | p_old | m_old]
  {
    bf16x8 m0 = *(const bf16x8 *)&sm_p[arow][g8];
    bf16x8 m1 = *(const bf16x8 *)&sm_p[arow][32 + g8];
    f32x4 a0 = {bias_m, bias_m, bias_m, bias_m};
    f32x4 a1 = {0.f, 0.f, 0.f, 0.f};
    f32x4 a2 = {0.f, 0.f, 0.f, 0.f};
    a0 = MFMA16(x0, Bm[0], a0);
    a1 = MFMA16(x1, Bm[1], a1);
    a2 = MFMA16(p0, Bm[2], a2);
    a0 = MFMA16(p1, Bm[3], a0);
    a1 = MFMA16(m0, Bm[4], a1);
    a2 = MFMA16(m1, Bm[5], a2);
    if (wr) {
#pragma unroll
      for (int r = 0; r < 4; ++r) {
        float z  = (a0[r] + a1[r]) + a2[r];
        float tv = fast_tanh(z);
        const int brow = gb * 4 + r;
        sm_c[brow][j] = brne(tv);
        if (FIN) mfin[brow][j] = tv;
      }
    }
  }
  __syncthreads();   // m_new visible to all waves
  // ---------------- price cell: in = [x | m_new | p_old]
  {
    bf16x8 n0 = *(const bf16x8 *)&sm_c[arow][g8];
    bf16x8 n1 = *(const bf16x8 *)&sm_c[arow][32 + g8];
    f32x4 a0 = {bias_p, bias_p, bias_p, bias_p};
    f32x4 a1 = {0.f, 0.f, 0.f, 0.f};
    f32x4 a2 = {0.f, 0.f, 0.f, 0.f};
    a0 = MFMA16(x0, Bp[0], a0);
    a1 = MFMA16(x1, Bp[1], a1);
    a2 = MFMA16(n0, Bp[2], a2);
    a0 = MFMA16(n1, Bp[3], a0);
    a1 = MFMA16(p0, Bp[4], a1);
    a2 = MFMA16(p1, Bp[5], a2);
    if (wr) {
#pragma unroll
      for (int r = 0; r < 4; ++r) {
        float z  = (a0[r] + a1[r]) + a2[r];
        float tv = fast_tanh(z);
        const int brow = gb * 4 + r;
        sp_c[brow][j] = brne(tv);
        if (FIN) pfin[brow][j] = tv;
      }
    }
  }
  __syncthreads();   // p_new visible; prev buffers free next step
}

__global__ __launch_bounds__(256, 2)
void mr_rnn_kernel(const float *__restrict__ x,
                   const float *__restrict__ mWih, const float *__restrict__ mWhh,
                   const float *__restrict__ mbih, const float *__restrict__ mbhh,
                   const float *__restrict__ pWih, const float *__restrict__ pWhh,
                   const float *__restrict__ pbih, const float *__restrict__ pbhh,
                   const float *__restrict__ plW,  const float *__restrict__ plb,
                   const float *__restrict__ mlW,  const float *__restrict__ mlb,
                   float *__restrict__ out, int B)
{
  __shared__ __align__(16) unsigned short sm[2][NB][72], sp[2][NB][72];
  __shared__ __align__(16) float s_mfin[NB][68], s_pfin[NB][68];

  const int tid  = threadIdx.x;
  const int lane = tid & 63;
  const int q    = tid >> 6;        // wave id -> output col tile
  const int l15  = lane & 15;
  const int arow = l15 & (NB - 1);  // batch row within block
  const int half = l15 >> 3;        // 0: carries x for even t, 1: for odd t
  const int g    = lane >> 4;       // k-group
  const int j    = q * 16 + l15;    // output feature owned by this lane's wave
  const int b0   = blockIdx.x * NB;
  const int g8   = g * 8;

  // ---- register-resident bf16 weight B-fragments: B[k][j] = W[j][k]
  bf16x8 Bm[6], Bp[6];
#pragma unroll
  for (int kt = 0; kt < 6; ++kt) {
    const int k0 = kt * 32 + g8;
#pragma unroll
    for (int i = 0; i < 8; ++i) {
      const int k = k0 + i;
      float wm = (k < 128) ? mWih[j * 128 + k] : mWhh[j * 64 + (k - 128)];
      float wp = (k < 128) ? pWih[j * 128 + k] : pWhh[j * 64 + (k - 128)];
      Bm[kt][i] = (short)brne(wm);
      Bp[kt][i] = (short)brne(wp);
    }
  }
  const float bias_m = mbih[j] + mbhh[j];
  const float bias_p = pbih[j] + pbhh[j];

  // ---- zero the t=-1 state buffers (parity index 1)
  for (int idx = tid; idx < NB * 72; idx += 256) {
    const int bb = idx / 72, kk = idx % 72;
    sm[1][bb][kk] = 0;
    sp[1][bb][kk] = 0;
  }

  // ---- x stream: lane covers batch b0+arow, step-parity `half`,
  //      features [g8,g8+8) and [32+g8,32+g8+8)
  const float *xrow = x + (size_t)(b0 + arow) * T_LEN * F_DIM;
  const float *px0  = xrow + (size_t)half * F_DIM;
  float4 A0 = *(const float4 *)(px0 + g8);
  float4 A1 = *(const float4 *)(px0 + g8 + 4);
  float4 A2 = *(const float4 *)(px0 + 32 + g8);
  float4 A3 = *(const float4 *)(px0 + 32 + g8 + 4);
  bf16x8 x0, x1;
  cvt8(A0, A1, x0);
  cvt8(A2, A3, x1);
  __syncthreads();   // zero-init visible

#pragma unroll 1
  for (int t = 0; t < T_LEN - 2; t += 2) {
    // prefetch this lane's next x (step t+2+half)
    const float *pf = xrow + (size_t)(t + 2 + half) * F_DIM;
    A0 = *(const float4 *)(pf + g8);
    A1 = *(const float4 *)(pf + g8 + 4);
    A2 = *(const float4 *)(pf + 32 + g8);
    A3 = *(const float4 *)(pf + 32 + g8 + 4);
    // step t (even): cur parity 0, prev 1
    step_cells<0, false>(arow, g, j, x0, x1, Bm, Bp, bias_m, bias_p,
                         sm[0], sm[1], sp[0], sp[1], s_mfin, s_pfin);
    // step t+1 (odd): cur parity 1, prev 0 — same x frags, other half valid
    step_cells<1, false>(arow, g, j, x0, x1, Bm, Bp, bias_m, bias_p,
                         sm[1], sm[0], sp[1], sp[0], s_mfin, s_pfin);
    cvt8(A0, A1, x0);
    cvt8(A2, A3, x1);
  }
  // ---- steps 510, 511 (no prefetch; 511 writes fp32 finals)
  step_cells<0, false>(arow, g, j, x0, x1, Bm, Bp, bias_m, bias_p,
                       sm[0], sm[1], sp[0], sp[1], s_mfin, s_pfin);
  step_cells<1, true>(arow, g, j, x0, x1, Bm, Bp, bias_m, bias_p,
                      sm[1], sm[0], sp[1], sp[0], s_mfin, s_pfin);

  // ---- heads (trailing __syncthreads inside step_cells orders s_*fin)
  if (tid < NB) {
    const int b = tid;
    float acc = plb[0];
#pragma unroll 1
    for (int k = 0; k < 64; ++k) acc += s_pfin[b][k] * plW[k];
    out[b0 + b] = acc;
  } else if (tid < NB + NB * 8) {
    const int r = tid - NB;
    const int b = r >> 3, e = r & 7;
    float acc = mlb[e];
#pragma unroll 1
    for (int k = 0; k < 64; ++k) acc += s_mfin[b][k] * mlW[e * 64 + k];
    out[(size_t)B + (size_t)(b0 + b) * 8 + e] = acc;
  }
}

extern "C" void kernel_launch(void* const* d_in, const int* in_sizes, int n_in,
                              void* d_out, int out_size, void* d_ws, size_t ws_size,
                              hipStream_t stream) {
  (void)n_in; (void)out_size; (void)d_ws; (void)ws_size;
  const float* x    = (const float*)d_in[0];
  const float* mWih = (const float*)d_in[1];
  const float* mWhh = (const float*)d_in[2];
  const float* mbih = (const float*)d_in[3];
  const float* mbhh = (const float*)d_in[4];
  const float* pWih = (const float*)d_in[5];
  const float* pWhh = (const float*)d_in[6];
  const float* pbih = (const float*)d_in[7];
  const float* pbhh = (const float*)d_in[8];
  const float* plW  = (const float*)d_in[9];
  const float* plb  = (const float*)d_in[10];
  const float* mlW  = (const float*)d_in[11];
  const float* mlb  = (const float*)d_in[12];
  const int B = in_sizes[0] / (T_LEN * F_DIM);
  const int nblk = B / NB;   // 512 blocks -> 2 blocks/CU -> 2 waves/SIMD
  mr_rnn_kernel<<<dim3(nblk), dim3(256), 0, stream>>>(
      x, mWih, mWhh, mbih, mbhh, pWih, pWhh, pbih, pbhh,
      plW, plb, mlW, mlb, (float*)d_out, B);
}

// Round 5
// 304.692 us; speedup vs baseline: 2.3646x; 1.5264x over previous
//
#include <hip/hip_runtime.h>

typedef short bf16x8 __attribute__((ext_vector_type(8)));
typedef float f32x4 __attribute__((ext_vector_type(4)));

#define MFMA16(a, b, c) __builtin_amdgcn_mfma_f32_16x16x32_bf16((a), (b), (c), 0, 0, 0)

static constexpr int T_LEN = 512;
static constexpr int F_DIM = 64;
static constexpr int NB    = 8;    // batch rows per block -> 512 blocks -> 2 blocks/CU
static constexpr float C1  = 2.885390081777927f;  // 2*log2(e)

// round-half-up fp32->bf16 (2 VALU ops; differs from RNE only on exact ties)
__device__ __forceinline__ unsigned short rhu(float f) {
  return (unsigned short)((__float_as_uint(f) + 0x8000u) >> 16);
}

// exact RNE (one-time weight conversion only)
__device__ __forceinline__ unsigned short brne(float f) {
  unsigned u = __float_as_uint(f);
  return (unsigned short)((u + 0x7fffu + ((u >> 16) & 1u)) >> 16);
}

__device__ __forceinline__ void cvt8(const float4 &a, const float4 &b, bf16x8 &o) {
  o[0] = (short)rhu(a.x); o[1] = (short)rhu(a.y);
  o[2] = (short)rhu(a.z); o[3] = (short)rhu(a.w);
  o[4] = (short)rhu(b.x); o[5] = (short)rhu(b.y);
  o[6] = (short)rhu(b.z); o[7] = (short)rhu(b.w);
}

// tanh(s + bias) with bias pre-folded: c2 = C1*bias.  6 VALU ops.
__device__ __forceinline__ float tanh_fold(float s, float c2) {
  float e  = __builtin_amdgcn_exp2f(__builtin_fmaf(s, C1, c2));
  float rc = __builtin_amdgcn_rcpf(e + 1.0f);
  return __builtin_fmaf(-2.0f, rc, 1.0f);
}

// One RNN step (m-cell then p-cell), all-bf16 operands, fp32 accum.
// PAR=0 (even t): valid C rows 0-7, writers g<2.  PAR=1 (odd t): valid C rows
// 8-15 (x frags of lanes l15>=8), writers g>=2.  A rows of the inactive half
// hold the OTHER step's x — harmless, their C rows are discarded.
template<int PAR, bool FIN>
__device__ __forceinline__ void step_cells(
    int arow, int g, int j,
    const bf16x8 &x0, const bf16x8 &x1,
    const bf16x8 (&Bm)[6], const bf16x8 (&Bp)[6],
    float c2m, float c2p,
    unsigned short (*sm_c)[72], unsigned short (*sm_p)[72],
    unsigned short (*sp_c)[72], unsigned short (*sp_p)[72],
    float (*mfin)[68], float (*pfin)[68])
{
  const int g8 = g * 8;
  const bool wr = (PAR == 0) ? (g < 2) : (g >= 2);
  const int gb  = (PAR == 0) ? g : (g - 2);
  // p_old fragments (used by both cells; buffer not rewritten this step)
  bf16x8 p0 = *(const bf16x8 *)&sp_p[arow][g8];
  bf16x8 p1 = *(const bf16x8 *)&sp_p[arow][32 + g8];

  // ---------------- metrics cell: in = [x | p_old | m_old]
  {
    bf16x8 m0 = *(const bf16x8 *)&sm_p[arow][g8];
    bf16x8 m1 = *(const bf16x8 *)&sm_p[arow][32 + g8];
    f32x4 a0 = {0.f, 0.f, 0.f, 0.f};
    f32x4 a1 = {0.f, 0.f, 0.f, 0.f};
    a0 = MFMA16(x0, Bm[0], a0);
    a1 = MFMA16(x1, Bm[1], a1);
    a0 = MFMA16(p0, Bm[2], a0);
    a1 = MFMA16(p1, Bm[3], a1);
    a0 = MFMA16(m0, Bm[4], a0);
    a1 = MFMA16(m1, Bm[5], a1);
    if (wr) {
#pragma unroll
      for (int r = 0; r < 4; ++r) {
        float tv = tanh_fold(a0[r] + a1[r], c2m);
        const int brow = gb * 4 + r;
        sm_c[brow][j] = rhu(tv);
        if (FIN) mfin[brow][j] = tv;
      }
    }
  }
  __syncthreads();   // m_new visible to all waves
  // ---------------- price cell: in = [x | m_new | p_old]
  {
    bf16x8 n0 = *(const bf16x8 *)&sm_c[arow][g8];
    bf16x8 n1 = *(const bf16x8 *)&sm_c[arow][32 + g8];
    f32x4 a0 = {0.f, 0.f, 0.f, 0.f};
    f32x4 a1 = {0.f, 0.f, 0.f, 0.f};
    a0 = MFMA16(x0, Bp[0], a0);
    a1 = MFMA16(x1, Bp[1], a1);
    a0 = MFMA16(n0, Bp[2], a0);
    a1 = MFMA16(n1, Bp[3], a1);
    a0 = MFMA16(p0, Bp[4], a0);
    a1 = MFMA16(p1, Bp[5], a1);
    if (wr) {
#pragma unroll
      for (int r = 0; r < 4; ++r) {
        float tv = tanh_fold(a0[r] + a1[r], c2p);
        const int brow = gb * 4 + r;
        sp_c[brow][j] = rhu(tv);
        if (FIN) pfin[brow][j] = tv;
      }
    }
  }
  __syncthreads();   // p_new visible; prev buffers free next step
}

__global__ __launch_bounds__(256, 2)
void mr_rnn_kernel(const float *__restrict__ x,
                   const float *__restrict__ mWih, const float *__restrict__ mWhh,
                   const float *__restrict__ mbih, const float *__restrict__ mbhh,
                   const float *__restrict__ pWih, const float *__restrict__ pWhh,
                   const float *__restrict__ pbih, const float *__restrict__ pbhh,
                   const float *__restrict__ plW,  const float *__restrict__ plb,
                   const float *__restrict__ mlW,  const float *__restrict__ mlb,
                   float *__restrict__ out, int B)
{
  __shared__ __align__(16) unsigned short sm[2][NB][72], sp[2][NB][72];
  __shared__ __align__(16) float s_mfin[NB][68], s_pfin[NB][68];

  const int tid  = threadIdx.x;
  const int lane = tid & 63;
  const int q    = tid >> 6;        // wave id -> output col tile
  const int l15  = lane & 15;
  const int arow = l15 & (NB - 1);  // batch row within block
  const int half = l15 >> 3;        // 0: carries x for even t, 1: for odd t
  const int g    = lane >> 4;       // k-group
  const int j    = q * 16 + l15;    // output feature owned by this lane's wave
  const int b0   = blockIdx.x * NB;
  const int g8   = g * 8;

  // ---- register-resident bf16 weight B-fragments: B[k][j] = W[j][k]
  bf16x8 Bm[6], Bp[6];
#pragma unroll
  for (int kt = 0; kt < 6; ++kt) {
    const int k0 = kt * 32 + g8;
#pragma unroll
    for (int i = 0; i < 8; ++i) {
      const int k = k0 + i;
      float wm = (k < 128) ? mWih[j * 128 + k] : mWhh[j * 64 + (k - 128)];
      float wp = (k < 128) ? pWih[j * 128 + k] : pWhh[j * 64 + (k - 128)];
      Bm[kt][i] = (short)brne(wm);
      Bp[kt][i] = (short)brne(wp);
    }
  }
  const float c2m = C1 * (mbih[j] + mbhh[j]);   // bias folded into exp2 arg
  const float c2p = C1 * (pbih[j] + pbhh[j]);

  // ---- zero the t=-1 state buffers (parity index 1)
  for (int idx = tid; idx < NB * 72; idx += 256) {
    const int bb = idx / 72, kk = idx % 72;
    sm[1][bb][kk] = 0;
    sp[1][bb][kk] = 0;
  }

  // ---- x stream: lane covers batch b0+arow, step-parity `half`,
  //      features [g8,g8+8) and [32+g8,32+g8+8)
  const float *xrow = x + (size_t)(b0 + arow) * T_LEN * F_DIM;
  const float *px0  = xrow + (size_t)half * F_DIM;
  float4 A0 = *(const float4 *)(px0 + g8);
  float4 A1 = *(const float4 *)(px0 + g8 + 4);
  float4 A2 = *(const float4 *)(px0 + 32 + g8);
  float4 A3 = *(const float4 *)(px0 + 32 + g8 + 4);
  bf16x8 x0, x1;
  cvt8(A0, A1, x0);
  cvt8(A2, A3, x1);
  __syncthreads();   // zero-init visible

#pragma unroll 1
  for (int t = 0; t < T_LEN - 2; t += 2) {
    // prefetch this lane's next x (step t+2+half)
    const float *pf = xrow + (size_t)(t + 2 + half) * F_DIM;
    A0 = *(const float4 *)(pf + g8);
    A1 = *(const float4 *)(pf + g8 + 4);
    A2 = *(const float4 *)(pf + 32 + g8);
    A3 = *(const float4 *)(pf + 32 + g8 + 4);
    // step t (even): cur parity 0, prev 1
    step_cells<0, false>(arow, g, j, x0, x1, Bm, Bp, c2m, c2p,
                         sm[0], sm[1], sp[0], sp[1], s_mfin, s_pfin);
    // step t+1 (odd): cur parity 1, prev 0 — same x frags, other half valid
    step_cells<1, false>(arow, g, j, x0, x1, Bm, Bp, c2m, c2p,
                         sm[1], sm[0], sp[1], sp[0], s_mfin, s_pfin);
    cvt8(A0, A1, x0);
    cvt8(A2, A3, x1);
  }
  // ---- steps 510, 511 (no prefetch; 511 writes fp32 finals)
  step_cells<0, false>(arow, g, j, x0, x1, Bm, Bp, c2m, c2p,
                       sm[0], sm[1], sp[0], sp[1], s_mfin, s_pfin);
  step_cells<1, true>(arow, g, j, x0, x1, Bm, Bp, c2m, c2p,
                      sm[1], sm[0], sp[1], sp[0], s_mfin, s_pfin);

  // ---- heads (trailing __syncthreads inside step_cells orders s_*fin)
  if (tid < NB) {
    const int b = tid;
    float acc = plb[0];
#pragma unroll 1
    for (int k = 0; k < 64; ++k) acc += s_pfin[b][k] * plW[k];
    out[b0 + b] = acc;
  } else if (tid < NB + NB * 8) {
    const int r = tid - NB;
    const int b = r >> 3, e = r & 7;
    float acc = mlb[e];
#pragma unroll 1
    for (int k = 0; k < 64; ++k) acc += s_mfin[b][k] * mlW[e * 64 + k];
    out[(size_t)B + (size_t)(b0 + b) * 8 + e] = acc;
  }
}

extern "C" void kernel_launch(void* const* d_in, const int* in_sizes, int n_in,
                              void* d_out, int out_size, void* d_ws, size_t ws_size,
                              hipStream_t stream) {
  (void)n_in; (void)out_size; (void)d_ws; (void)ws_size;
  const float* x    = (const float*)d_in[0];
  const float* mWih = (const float*)d_in[1];
  const float* mWhh = (const float*)d_in[2];
  const float* mbih = (const float*)d_in[3];
  const float* mbhh = (const float*)d_in[4];
  const float* pWih = (const float*)d_in[5];
  const float* pWhh = (const float*)d_in[6];
  const float* pbih = (const float*)d_in[7];
  const float* pbhh = (const float*)d_in[8];
  const float* plW  = (const float*)d_in[9];
  const float* plb  = (const float*)d_in[10];
  const float* mlW  = (const float*)d_in[11];
  const float* mlb  = (const float*)d_in[12];
  const int B = in_sizes[0] / (T_LEN * F_DIM);
  const int nblk = B / NB;   // 512 blocks -> 2 blocks/CU -> 2 waves/SIMD
  mr_rnn_kernel<<<dim3(nblk), dim3(256), 0, stream>>>(
      x, mWih, mWhh, mbih, mbhh, pWih, pWhh, pbih, pbhh,
      plW, plb, mlW, mlb, (float*)d_out, B);
}

// Round 6
// 286.983 us; speedup vs baseline: 2.5105x; 1.0617x over previous
//
#include <hip/hip_runtime.h>

typedef short bf16x8 __attribute__((ext_vector_type(8)));
typedef float f32x4 __attribute__((ext_vector_type(4)));
typedef int   int4v  __attribute__((ext_vector_type(4)));

#define MFMA16(a, b, c) __builtin_amdgcn_mfma_f32_16x16x32_bf16((a), (b), (c), 0, 0, 0)

static constexpr int T_LEN = 512;
static constexpr int F_DIM = 64;
static constexpr int NB    = 8;    // batch rows per block -> 512 blocks -> 2 blocks/CU
static constexpr float C1  = 2.885390081777927f;  // 2*log2(e)

// exact RNE (one-time weight conversion only)
__device__ __forceinline__ unsigned short brne(float f) {
  unsigned u = __float_as_uint(f);
  return (unsigned short)((u + 0x7fffu + ((u >> 16) & 1u)) >> 16);
}

// v_cvt_pk_bf16_f32: packs 2 fp32 -> 2 bf16 (RNE) in one dword. No builtin (m240).
__device__ __forceinline__ int cvtpk(float lo, float hi) {
  int r;
  asm("v_cvt_pk_bf16_f32 %0, %1, %2" : "=v"(r) : "v"(lo), "v"(hi));
  return r;
}

// 8 fp32 -> bf16x8 fragment via 4 cvt_pk
__device__ __forceinline__ bf16x8 cvt8(const float4 &a, const float4 &b) {
  int4v d = {cvtpk(a.x, a.y), cvtpk(a.z, a.w), cvtpk(b.x, b.y), cvtpk(b.z, b.w)};
  union { int4v i; bf16x8 h; } u;
  u.i = d;
  return u.h;
}

// v_permlane32_swap_b32: r[0] = {a[0:31], b[0:31]}, r[1] = {a[32:63], b[32:63]}
__device__ __forceinline__ void swap32(float &a, float &b) {
  auto r = __builtin_amdgcn_permlane32_swap(__float_as_int(a), __float_as_int(b),
                                            false, false);
  a = __int_as_float(r[0]);
  b = __int_as_float(r[1]);
}

// DPP quad_perm(1,0,3,2): fetch xor-1 lane neighbor (all lanes active)
__device__ __forceinline__ float xor1(float v) {
  return __int_as_float(__builtin_amdgcn_mov_dpp(__float_as_int(v), 0xB1, 0xF, 0xF, true));
}

// tanh(s + bias) with bias pre-folded: c2 = C1*bias
__device__ __forceinline__ float tanh_fold(float s, float c2) {
  float e  = __builtin_amdgcn_exp2f(__builtin_fmaf(s, C1, c2));
  float rc = __builtin_amdgcn_rcpf(e + 1.0f);
  return __builtin_fmaf(-2.0f, rc, 1.0f);
}

// Epilogue: redistribute 8 half-exec pre-acts to 2 full-exec values, tanh,
// pack pairs along j, write conflict-free b32s.  wofs/evn/rowA precomputed.
// Row formula (both parities): value A -> row rowA, value B -> row rowA+1.
template<int PAR, bool FIN>
__device__ __forceinline__ void epilogue(
    const f32x4 &a0, const f32x4 &a1, float c2,
    unsigned short (*buf)[72], float (*fin)[68],
    int wofs, bool evn, int rowA, int j)
{
  float z0 = a0[0] + a1[0];
  float z1 = a0[1] + a1[1];
  float z2 = a0[2] + a1[2];
  float z3 = a0[3] + a1[3];
  swap32(z0, z2);            // z0={z0.lo,z2.lo}, z2={z0.hi,z2.hi}
  swap32(z1, z3);
  float sA = (PAR == 0) ? z0 : z2;
  float sB = (PAR == 0) ? z1 : z3;
  float tA = tanh_fold(sA, c2);
  float tB = tanh_fold(sB, c2);
  float nA = xor1(tA);
  float nB = xor1(tB);
  if (evn) {                 // even-j lanes write packed (j, j+1) dwords
    unsigned short *p = &buf[0][0];
    *(unsigned *)(p + wofs)      = (unsigned)cvtpk(tA, nA);
    *(unsigned *)(p + wofs + 72) = (unsigned)cvtpk(tB, nB);
  }
  if (FIN) {                 // fp32 finals, all lanes (rows rowA, rowA+1 at col j)
    fin[rowA][j]     = tA;
    fin[rowA + 1][j] = tB;
  }
}

// One RNN step (m-cell then p-cell), all-bf16 operands, fp32 accum.
// PAR=0 (even t): valid C rows 0-7 live in lanes 0-31.  PAR=1: lanes 32-63.
template<int PAR, bool FIN>
__device__ __forceinline__ void step_cells(
    int arow, int g8, int j, int wofs, bool evn, int rowA,
    const bf16x8 &x0, const bf16x8 &x1,
    const bf16x8 (&Bm)[6], const bf16x8 (&Bp)[6],
    float c2m, float c2p, const f32x4 &Z,
    unsigned short (*sm_c)[72], unsigned short (*sm_p)[72],
    unsigned short (*sp_c)[72], unsigned short (*sp_p)[72],
    float (*mfin)[68], float (*pfin)[68])
{
  // p_old fragments (used by both cells; buffer not rewritten this step)
  bf16x8 p0 = *(const bf16x8 *)&sp_p[arow][g8];
  bf16x8 p1 = *(const bf16x8 *)&sp_p[arow][32 + g8];

  // ---------------- metrics cell: in = [x | p_old | m_old]
  {
    bf16x8 m0 = *(const bf16x8 *)&sm_p[arow][g8];
    bf16x8 m1 = *(const bf16x8 *)&sm_p[arow][32 + g8];
    f32x4 a0 = MFMA16(x0, Bm[0], Z);
    f32x4 a1 = MFMA16(x1, Bm[1], Z);
    a0 = MFMA16(p0, Bm[2], a0);
    a1 = MFMA16(p1, Bm[3], a1);
    a0 = MFMA16(m0, Bm[4], a0);
    a1 = MFMA16(m1, Bm[5], a1);
    epilogue<PAR, FIN>(a0, a1, c2m, sm_c, mfin, wofs, evn, rowA, j);
  }
  __syncthreads();   // m_new visible to all waves
  // ---------------- price cell: in = [x | m_new | p_old]
  {
    bf16x8 n0 = *(const bf16x8 *)&sm_c[arow][g8];
    bf16x8 n1 = *(const bf16x8 *)&sm_c[arow][32 + g8];
    f32x4 a0 = MFMA16(x0, Bp[0], Z);
    f32x4 a1 = MFMA16(x1, Bp[1], Z);
    a0 = MFMA16(n0, Bp[2], a0);
    a1 = MFMA16(n1, Bp[3], a1);
    a0 = MFMA16(p0, Bp[4], a0);
    a1 = MFMA16(p1, Bp[5], a1);
    epilogue<PAR, FIN>(a0, a1, c2p, sp_c, pfin, wofs, evn, rowA, j);
  }
  __syncthreads();   // p_new visible; prev buffers free next step
}

__global__ __launch_bounds__(256, 2)
void mr_rnn_kernel(const float *__restrict__ x,
                   const float *__restrict__ mWih, const float *__restrict__ mWhh,
                   const float *__restrict__ mbih, const float *__restrict__ mbhh,
                   const float *__restrict__ pWih, const float *__restrict__ pWhh,
                   const float *__restrict__ pbih, const float *__restrict__ pbhh,
                   const float *__restrict__ plW,  const float *__restrict__ plb,
                   const float *__restrict__ mlW,  const float *__restrict__ mlb,
                   float *__restrict__ out, int B)
{
  __shared__ __align__(16) unsigned short sm[2][NB][72], sp[2][NB][72];
  __shared__ __align__(16) float s_mfin[NB][68], s_pfin[NB][68];

  const int tid  = threadIdx.x;
  const int lane = tid & 63;
  const int q    = tid >> 6;        // wave id -> output col tile
  const int l15  = lane & 15;
  const int arow = l15 & (NB - 1);  // batch row within block
  const int half = l15 >> 3;        // 0: carries x for even t, 1: for odd t
  const int g    = lane >> 4;       // k-group
  const int j    = q * 16 + l15;    // output feature owned by this lane's wave
  const int b0   = blockIdx.x * NB;
  const int g8   = g * 8;
  // epilogue lane constants: rows (rowA, rowA+1), packed write offset (shorts)
  const int rowA = ((lane & 16) >> 2) | ((lane >> 5) << 1);  // 4*gb + 2*(lane>=32)
  const bool evn = (l15 & 1) == 0;
  const int wofs = rowA * 72 + (j & ~1);

  // ---- register-resident bf16 weight B-fragments: B[k][j] = W[j][k]
  bf16x8 Bm[6], Bp[6];
#pragma unroll
  for (int kt = 0; kt < 6; ++kt) {
    const int k0 = kt * 32 + g8;
#pragma unroll
    for (int i = 0; i < 8; ++i) {
      const int k = k0 + i;
      float wm = (k < 128) ? mWih[j * 128 + k] : mWhh[j * 64 + (k - 128)];
      float wp = (k < 128) ? pWih[j * 128 + k] : pWhh[j * 64 + (k - 128)];
      Bm[kt][i] = (short)brne(wm);
      Bp[kt][i] = (short)brne(wp);
    }
  }
  const float c2m = C1 * (mbih[j] + mbhh[j]);   // bias folded into exp2 arg
  const float c2p = C1 * (pbih[j] + pbhh[j]);
  const f32x4 Z = {0.f, 0.f, 0.f, 0.f};         // hoisted accumulator seed

  // ---- zero the t=-1 state buffers (parity index 1)
  for (int idx = tid; idx < NB * 72; idx += 256) {
    const int bb = idx / 72, kk = idx % 72;
    sm[1][bb][kk] = 0;
    sp[1][bb][kk] = 0;
  }

  // ---- x stream: lane covers batch b0+arow, step-parity `half`,
  //      features [g8,g8+8) and [32+g8,32+g8+8); pointer-bump addressing
  const float *pxl = x + ((size_t)(b0 + arow) * T_LEN + half) * F_DIM + g8;
  float4 A0 = *(const float4 *)(pxl);
  float4 A1 = *(const float4 *)(pxl + 4);
  float4 A2 = *(const float4 *)(pxl + 32);
  float4 A3 = *(const float4 *)(pxl + 36);
  bf16x8 x0 = cvt8(A0, A1);
  bf16x8 x1 = cvt8(A2, A3);
  __syncthreads();   // zero-init visible

#pragma unroll 1
  for (int t = 0; t < T_LEN - 2; t += 2) {
    // prefetch this lane's next x (step t+2+half)
    pxl += 2 * F_DIM;
    A0 = *(const float4 *)(pxl);
    A1 = *(const float4 *)(pxl + 4);
    A2 = *(const float4 *)(pxl + 32);
    A3 = *(const float4 *)(pxl + 36);
    // step t (even): cur parity 0, prev 1
    step_cells<0, false>(arow, g8, j, wofs, evn, rowA, x0, x1, Bm, Bp, c2m, c2p, Z,
                         sm[0], sm[1], sp[0], sp[1], s_mfin, s_pfin);
    // step t+1 (odd): cur parity 1, prev 0 — same x frags, other half valid
    step_cells<1, false>(arow, g8, j, wofs, evn, rowA, x0, x1, Bm, Bp, c2m, c2p, Z,
                         sm[1], sm[0], sp[1], sp[0], s_mfin, s_pfin);
    x0 = cvt8(A0, A1);
    x1 = cvt8(A2, A3);
  }
  // ---- steps 510, 511 (no prefetch; 511 writes fp32 finals)
  step_cells<0, false>(arow, g8, j, wofs, evn, rowA, x0, x1, Bm, Bp, c2m, c2p, Z,
                       sm[0], sm[1], sp[0], sp[1], s_mfin, s_pfin);
  step_cells<1, true>(arow, g8, j, wofs, evn, rowA, x0, x1, Bm, Bp, c2m, c2p, Z,
                      sm[1], sm[0], sp[1], sp[0], s_mfin, s_pfin);

  // ---- heads (trailing __syncthreads inside step_cells orders s_*fin)
  if (tid < NB) {
    const int b = tid;
    float acc = plb[0];
#pragma unroll 1
    for (int k = 0; k < 64; ++k) acc += s_pfin[b][k] * plW[k];
    out[b0 + b] = acc;
  } else if (tid < NB + NB * 8) {
    const int r = tid - NB;
    const int b = r >> 3, e = r & 7;
    float acc = mlb[e];
#pragma unroll 1
    for (int k = 0; k < 64; ++k) acc += s_mfin[b][k] * mlW[e * 64 + k];
    out[(size_t)B + (size_t)(b0 + b) * 8 + e] = acc;
  }
}

extern "C" void kernel_launch(void* const* d_in, const int* in_sizes, int n_in,
                              void* d_out, int out_size, void* d_ws, size_t ws_size,
                              hipStream_t stream) {
  (void)n_in; (void)out_size; (void)d_ws; (void)ws_size;
  const float* x    = (const float*)d_in[0];
  const float* mWih = (const float*)d_in[1];
  const float* mWhh = (const float*)d_in[2];
  const float* mbih = (const float*)d_in[3];
  const float* mbhh = (const float*)d_in[4];
  const float* pWih = (const float*)d_in[5];
  const float* pWhh = (const float*)d_in[6];
  const float* pbih = (const float*)d_in[7];
  const float* pbhh = (const float*)d_in[8];
  const float* plW  = (const float*)d_in[9];
  const float* plb  = (const float*)d_in[10];
  const float* mlW  = (const float*)d_in[11];
  const float* mlb  = (const float*)d_in[12];
  const int B = in_sizes[0] / (T_LEN * F_DIM);
  const int nblk = B / NB;   // 512 blocks -> 2 blocks/CU -> 2 waves/SIMD
  mr_rnn_kernel<<<dim3(nblk), dim3(256), 0, stream>>>(
      x, mWih, mWhh, mbih, mbhh, pWih, pWhh, pbih, pbhh,
      plW, plb, mlW, mlb, (float*)d_out, B);
}